// Round 3
// baseline (124.126 us; speedup 1.0000x reference)
//
#include <hip/hip_runtime.h>

typedef __bf16 bf16_t;
typedef __bf16 bf16x8 __attribute__((ext_vector_type(8)));
typedef __bf16 bf16x4 __attribute__((ext_vector_type(4)));
typedef float f32x4 __attribute__((ext_vector_type(4)));

#define MFMA_BF16(a, b, c) __builtin_amdgcn_mfma_f32_16x16x32_bf16((a), (b), (c), 0, 0, 0)

__device__ __forceinline__ void gload16(const bf16_t* g, bf16_t* l) {
  __builtin_amdgcn_global_load_lds(
      (__attribute__((address_space(1))) void*)(g),
      (__attribute__((address_space(3))) void*)(l), 16, 0, 0);
}

// ---------------------------------------------------------------------------
// Cast x and the 4 weights f32 -> bf16.  wbf layout: [Wq | Wk | Wv | Wo]
// ---------------------------------------------------------------------------
__global__ void cast_all(const float* __restrict__ x, const float* __restrict__ wk,
                         const float* __restrict__ wq, const float* __restrict__ wv,
                         const float* __restrict__ wo, bf16_t* __restrict__ xbf,
                         bf16_t* __restrict__ wbf) {
  const size_t NX = 4194304, NW = 1048576;
  size_t i = (size_t)blockIdx.x * blockDim.x + threadIdx.x;
  const size_t total4 = (NX + 4 * NW) / 4;
  const size_t stride = (size_t)gridDim.x * blockDim.x;
  for (; i < total4; i += stride) {
    size_t f = i * 4;
    const float* src;
    bf16_t* dst;
    if (f < NX) {
      src = x + f;
      dst = xbf + f;
    } else {
      size_t g = f - NX;
      size_t wsel = g >> 20;
      size_t off = g & (NW - 1);
      dst = wbf + g;
      src = (wsel == 0) ? wq + off : (wsel == 1) ? wk + off : (wsel == 2) ? wv + off : wo + off;
    }
    float4 v = *(const float4*)src;
    bf16x4 o;
    o[0] = (bf16_t)v.x; o[1] = (bf16_t)v.y; o[2] = (bf16_t)v.z; o[3] = (bf16_t)v.w;
    *(bf16x4*)dst = o;
  }
}

// ---------------------------------------------------------------------------
// NT GEMM: C[m][n] = sum_k A[m][k] * W[n][k].  128x128 tile, BK=32, 4 waves.
// sect = blockIdx.y / blocksPerSect selects the 1024-col weight section.
// If vtb != nullptr, sect==2 (the V projection) is written TRANSPOSED to
// vtb as [bh=32][d=64][l=2048] bf16 (vectorized over 4 consecutive l).
// ---------------------------------------------------------------------------
template <typename TOUT>
__global__ __launch_bounds__(256) void gemm_nt(const bf16_t* __restrict__ A,
                                               const bf16_t* __restrict__ W,
                                               TOUT* __restrict__ C, int K, int ldc,
                                               int blocksPerSect, bf16_t* __restrict__ vtb) {
  __shared__ bf16_t As[128 * 32];
  __shared__ bf16_t Bs[128 * 32];
  const int t = threadIdx.x;
  const int l = t & 63, w = t >> 6;
  const int wm = w >> 1, wn = w & 1;
  const int lr = l & 15, lg = l >> 4;
  const int bm = blockIdx.x;
  const int by = blockIdx.y;
  const int sect = by / blocksPerSect;
  const int bn = by - sect * blocksPerSect;
  const bf16_t* Wp = W + ((size_t)sect << 20);
  const int n0 = sect * 1024 + bn * 128;

  const bf16_t* ag = A + (size_t)(bm * 128 + (t >> 2)) * K + (t & 3) * 8;
  const bf16_t* bg = Wp + (size_t)(bn * 128 + (t >> 2)) * K + (t & 3) * 8;
  const size_t rs64 = (size_t)64 * K;

  f32x4 acc[4][4];
#pragma unroll
  for (int i = 0; i < 4; ++i)
#pragma unroll
    for (int j = 0; j < 4; ++j) acc[i][j] = (f32x4){0.f, 0.f, 0.f, 0.f};

  for (int k0 = 0; k0 < K; k0 += 32) {
    __syncthreads();
    gload16(ag, As + t * 8);
    gload16(ag + rs64, As + 2048 + t * 8);
    gload16(bg, Bs + t * 8);
    gload16(bg + rs64, Bs + 2048 + t * 8);
    ag += 32;
    bg += 32;
    __syncthreads();
    bf16x8 af[4], bfr[4];
#pragma unroll
    for (int mf = 0; mf < 4; ++mf)
      af[mf] = *(const bf16x8*)(As + (wm * 64 + mf * 16 + lr) * 32 + lg * 8);
#pragma unroll
    for (int nf = 0; nf < 4; ++nf)
      bfr[nf] = *(const bf16x8*)(Bs + (wn * 64 + nf * 16 + lr) * 32 + lg * 8);
#pragma unroll
    for (int mf = 0; mf < 4; ++mf)
#pragma unroll
      for (int nf = 0; nf < 4; ++nf)
        acc[mf][nf] = MFMA_BF16(af[mf], bfr[nf], acc[mf][nf]);
  }

  if (vtb != nullptr && sect == 2) {
#pragma unroll
    for (int mf = 0; mf < 4; ++mf)
#pragma unroll
      for (int nf = 0; nf < 4; ++nf) {
        int row0 = bm * 128 + wm * 64 + mf * 16 + lg * 4;
        int colg = bn * 128 + wn * 64 + nf * 16 + lr;
        int bb = row0 >> 11, ll = row0 & 2047;
        size_t vaddr = ((size_t)((bb * 16 + (colg >> 6)) * 64 + (colg & 63))) * 2048 + ll;
        bf16x4 pk;
#pragma unroll
        for (int j = 0; j < 4; ++j) pk[j] = (bf16_t)acc[mf][nf][j];
        *(bf16x4*)(vtb + vaddr) = pk;
      }
  } else {
#pragma unroll
    for (int mf = 0; mf < 4; ++mf)
#pragma unroll
      for (int nf = 0; nf < 4; ++nf)
#pragma unroll
        for (int j = 0; j < 4; ++j) {
          int row = bm * 128 + wm * 64 + mf * 16 + lg * 4 + j;
          int col = n0 + wn * 64 + nf * 16 + lr;
          C[(size_t)row * ldc + col] = (TOUT)acc[mf][nf][j];
        }
  }
}

// ---------------------------------------------------------------------------
// Flash attention (causal), swapped QK^T, causal q-tile PAIRING + double-buffer.
// Block = 4 waves; handles q-tiles qhi=31-p (part 0, always) and qlo=p
// (part 1, while kt<=qlo): exactly 33 compute-tiles per block, uniform.
// ---------------------------------------------------------------------------
template <int NP>
__device__ __forceinline__ void attn_tile(const bf16_t* Kb, const bf16_t* Vb, bf16_t* Pw,
                                          const bf16x8 (&qf)[2][2], f32x4 (&acc)[2][4],
                                          float (&m_r)[2], float (&l_r)[2], int qloc,
                                          const int (&diag)[2], int lr, int lg) {
  f32x4 sc[2][4];
#pragma unroll
  for (int pp = 0; pp < NP; ++pp)
#pragma unroll
    for (int nf = 0; nf < 4; ++nf) sc[pp][nf] = (f32x4){0.f, 0.f, 0.f, 0.f};
#pragma unroll
  for (int nf = 0; nf < 4; ++nf) {
    int row = nf * 16 + lr, r7 = row & 7;
    bf16x8 kf0 = *(const bf16x8*)(Kb + row * 64 + (lg ^ r7) * 8);
    bf16x8 kf1 = *(const bf16x8*)(Kb + row * 64 + ((lg ^ 4) ^ r7) * 8);
#pragma unroll
    for (int pp = 0; pp < NP; ++pp) {
      sc[pp][nf] = MFMA_BF16(kf0, qf[pp][0], sc[pp][nf]);
      sc[pp][nf] = MFMA_BF16(kf1, qf[pp][1], sc[pp][nf]);
    }
  }
#pragma unroll
  for (int pp = 0; pp < NP; ++pp) {
    float s[16];
#pragma unroll
    for (int nf = 0; nf < 4; ++nf)
#pragma unroll
      for (int j = 0; j < 4; ++j) s[nf * 4 + j] = sc[pp][nf][j];
    if (diag[pp]) {
#pragma unroll
      for (int nf = 0; nf < 4; ++nf)
#pragma unroll
        for (int j = 0; j < 4; ++j)
          if (nf * 16 + lg * 4 + j > qloc) s[nf * 4 + j] = -1e30f;
    }
    float t0 = fmaxf(fmaxf(s[0], s[1]), fmaxf(s[2], s[3]));
    float t1 = fmaxf(fmaxf(s[4], s[5]), fmaxf(s[6], s[7]));
    float t2 = fmaxf(fmaxf(s[8], s[9]), fmaxf(s[10], s[11]));
    float t3 = fmaxf(fmaxf(s[12], s[13]), fmaxf(s[14], s[15]));
    float m16 = fmaxf(fmaxf(t0, t1), fmaxf(t2, t3));
    float rm = fmaxf(m16, __shfl_xor(m16, 16));
    rm = fmaxf(rm, __shfl_xor(rm, 32));
    if (!__all(rm - m_r[pp] <= 8.f)) {  // defer-max: rescale only on real growth
      float mnew = fmaxf(m_r[pp], rm);
      float sf = __expf(m_r[pp] - mnew);
      m_r[pp] = mnew;
      l_r[pp] *= sf;
#pragma unroll
      for (int df = 0; df < 4; ++df)
#pragma unroll
        for (int j = 0; j < 4; ++j) acc[pp][df][j] *= sf;
    }
    float p[16], ps = 0.f;
#pragma unroll
    for (int i = 0; i < 16; ++i) {
      p[i] = __expf(s[i] - m_r[pp]);
      ps += p[i];
    }
    ps += __shfl_xor(ps, 16);
    ps += __shfl_xor(ps, 32);
    l_r[pp] += ps;
#pragma unroll
    for (int nf = 0; nf < 4; ++nf) {
      bf16x4 pk;
#pragma unroll
      for (int j = 0; j < 4; ++j) pk[j] = (bf16_t)p[nf * 4 + j];
      *(bf16x4*)(Pw + pp * 1152 + lr * 72 + nf * 16 + lg * 4) = pk;
    }
  }
  bf16x8 pb[2][2];
#pragma unroll
  for (int pp = 0; pp < NP; ++pp) {
    pb[pp][0] = *(const bf16x8*)(Pw + pp * 1152 + lr * 72 + lg * 8);
    pb[pp][1] = *(const bf16x8*)(Pw + pp * 1152 + lr * 72 + 32 + lg * 8);
  }
#pragma unroll
  for (int df = 0; df < 4; ++df) {
    int arow = df * 16 + lr, r7 = arow & 7;
    bf16x8 vf0 = *(const bf16x8*)(Vb + arow * 64 + (lg ^ r7) * 8);
    bf16x8 vf1 = *(const bf16x8*)(Vb + arow * 64 + ((lg ^ 4) ^ r7) * 8);
#pragma unroll
    for (int pp = 0; pp < NP; ++pp) {
      acc[pp][df] = MFMA_BF16(vf0, pb[pp][0], acc[pp][df]);
      acc[pp][df] = MFMA_BF16(vf1, pb[pp][1], acc[pp][df]);
    }
  }
}

__global__ __launch_bounds__(256) void attn_fwd(const bf16_t* __restrict__ qk,
                                                const bf16_t* __restrict__ vt,
                                                bf16_t* __restrict__ out) {
  __shared__ bf16_t Ks[2][4096];
  __shared__ bf16_t Vts[2][4096];
  __shared__ bf16_t Pt[4][2304];
  const int t = threadIdx.x, l = t & 63, w = t >> 6;
  const int lr = l & 15, lg = l >> 4;
  const int bh = blockIdx.x;
  const int b = bh >> 4, h = bh & 15;
  const int pr = blockIdx.y;  // pair index 0..15
  const int qlo = pr, qhi = 31 - pr;
  const int qtile[2] = {qhi, qlo};
  const int qloc = w * 16 + lr;

  // staging addresses (swizzle pre-applied on global source; LDS stays linear)
  const int srow = t >> 3, sc8 = t & 7;
  const int cs = sc8 ^ (srow & 7);
  const bf16_t* kbase = qk + ((size_t)(b * 2048 + srow)) * 2048 + 1024 + h * 64 + cs * 8;
  const bf16_t* vbase = vt + ((size_t)(bh * 64 + srow)) * 2048 + cs * 8;
  bf16_t* Pw = &Pt[w][0];

#define STAGE(ktile, buf)                                              \
  do {                                                                 \
    const bf16_t* ks_ = kbase + (size_t)(ktile) * (64 * 2048);         \
    const bf16_t* vs_ = vbase + (size_t)(ktile) * 64;                  \
    gload16(ks_, &Ks[buf][t * 8]);                                     \
    gload16(ks_ + (size_t)32 * 2048, &Ks[buf][2048 + t * 8]);          \
    gload16(vs_, &Vts[buf][t * 8]);                                    \
    gload16(vs_ + (size_t)32 * 2048, &Vts[buf][2048 + t * 8]);         \
  } while (0)

  // Q fragments for both parts, pre-scaled by 1/8 (exact in bf16)
  bf16x8 qf[2][2];
#pragma unroll
  for (int pp = 0; pp < 2; ++pp) {
    const bf16_t* Qg =
        qk + (size_t)(b * 2048 + qtile[pp] * 64 + w * 16 + lr) * 2048 + h * 64 + lg * 8;
    qf[pp][0] = *(const bf16x8*)(Qg);
    qf[pp][1] = *(const bf16x8*)(Qg + 32);
#pragma unroll
    for (int j = 0; j < 8; ++j) {
      qf[pp][0][j] = (bf16_t)((float)qf[pp][0][j] * 0.125f);
      qf[pp][1][j] = (bf16_t)((float)qf[pp][1][j] * 0.125f);
    }
  }

  f32x4 acc[2][4];
#pragma unroll
  for (int pp = 0; pp < 2; ++pp)
#pragma unroll
    for (int df = 0; df < 4; ++df) acc[pp][df] = (f32x4){0.f, 0.f, 0.f, 0.f};
  float m_r[2] = {-1e30f, -1e30f};
  float l_r[2] = {0.f, 0.f};

  STAGE(0, 0);
  __syncthreads();

  int cur = 0;
  for (int kt = 0; kt <= qhi; ++kt) {
    if (kt < qhi) STAGE(kt + 1, cur ^ 1);
    const int diag[2] = {kt == qhi, kt == qlo};
    if (kt <= qlo)
      attn_tile<2>(&Ks[cur][0], &Vts[cur][0], Pw, qf, acc, m_r, l_r, qloc, diag, lr, lg);
    else
      attn_tile<1>(&Ks[cur][0], &Vts[cur][0], Pw, qf, acc, m_r, l_r, qloc, diag, lr, lg);
    __syncthreads();
    cur ^= 1;
  }
#undef STAGE

#pragma unroll
  for (int pp = 0; pp < 2; ++pp) {
    float inv = 1.f / l_r[pp];
    int qrow = qtile[pp] * 64 + w * 16 + lr;
#pragma unroll
    for (int df = 0; df < 4; ++df) {
      bf16x4 o;
#pragma unroll
      for (int j = 0; j < 4; ++j) o[j] = (bf16_t)(acc[pp][df][j] * inv);
      *(bf16x4*)(out + (size_t)(b * 2048 + qrow) * 1024 + h * 64 + df * 16 + lg * 4) = o;
    }
  }
}

// ---------------------------------------------------------------------------
extern "C" void kernel_launch(void* const* d_in, const int* in_sizes, int n_in,
                              void* d_out, int out_size, void* d_ws, size_t ws_size,
                              hipStream_t stream) {
  const float* x = (const float*)d_in[0];
  const float* wk = (const float*)d_in[1];
  const float* wq = (const float*)d_in[2];
  const float* wv = (const float*)d_in[3];
  const float* wo = (const float*)d_in[4];

  bf16_t* xbf = (bf16_t*)d_ws;           // 4 Mi elems (8 MB)
  bf16_t* wbf = xbf + 4194304;           // 4 Mi elems (8 MB): [Wq|Wk|Wv|Wo]
  bf16_t* qkbf = wbf + 4194304;          // 8 Mi elems (16 MB): [Q|K] cols
  bf16_t* vtbuf = qkbf + 8388608;        // 4 Mi elems (8 MB): V transposed
  bf16_t* attnbf = xbf;                  // alias: xbf dead after QKV gemm
  float* out = (float*)d_out;

  cast_all<<<dim3(2048), dim3(256), 0, stream>>>(x, wk, wq, wv, wo, xbf, wbf);
  gemm_nt<bf16_t><<<dim3(32, 24), dim3(256), 0, stream>>>(xbf, wbf, qkbf, 1024, 2048, 8, vtbuf);
  attn_fwd<<<dim3(32, 16), dim3(256), 0, stream>>>(qkbf, vtbuf, attnbf);
  gemm_nt<float><<<dim3(32, 8), dim3(256), 0, stream>>>(attnbf, wbf + 3 * 1048576, out, 1024,
                                                        1024, 8, (bf16_t*)nullptr);
}

// Round 4
// 120.696 us; speedup vs baseline: 1.0284x; 1.0284x over previous
//
#include <hip/hip_runtime.h>

typedef __bf16 bf16_t;
typedef __bf16 bf16x8 __attribute__((ext_vector_type(8)));
typedef __bf16 bf16x4 __attribute__((ext_vector_type(4)));
typedef float f32x4 __attribute__((ext_vector_type(4)));

#define MFMA_BF16(a, b, c) __builtin_amdgcn_mfma_f32_16x16x32_bf16((a), (b), (c), 0, 0, 0)
#define LOG2E 1.44269504088896f

__device__ __forceinline__ void gload16(const bf16_t* g, bf16_t* l) {
  __builtin_amdgcn_global_load_lds(
      (__attribute__((address_space(1))) void*)(g),
      (__attribute__((address_space(3))) void*)(l), 16, 0, 0);
}

// ---------------------------------------------------------------------------
// Cast x and the 4 weights f32 -> bf16.  wbf layout: [Wq | Wk | Wv | Wo]
// ---------------------------------------------------------------------------
__global__ void cast_all(const float* __restrict__ x, const float* __restrict__ wk,
                         const float* __restrict__ wq, const float* __restrict__ wv,
                         const float* __restrict__ wo, bf16_t* __restrict__ xbf,
                         bf16_t* __restrict__ wbf) {
  const size_t NX = 4194304, NW = 1048576;
  size_t i = (size_t)blockIdx.x * blockDim.x + threadIdx.x;
  const size_t total4 = (NX + 4 * NW) / 4;
  const size_t stride = (size_t)gridDim.x * blockDim.x;
  for (; i < total4; i += stride) {
    size_t f = i * 4;
    const float* src;
    bf16_t* dst;
    if (f < NX) {
      src = x + f;
      dst = xbf + f;
    } else {
      size_t g = f - NX;
      size_t wsel = g >> 20;
      size_t off = g & (NW - 1);
      dst = wbf + g;
      src = (wsel == 0) ? wq + off : (wsel == 1) ? wk + off : (wsel == 2) ? wv + off : wo + off;
    }
    float4 v = *(const float4*)src;
    bf16x4 o;
    o[0] = (bf16_t)v.x; o[1] = (bf16_t)v.y; o[2] = (bf16_t)v.z; o[3] = (bf16_t)v.w;
    *(bf16x4*)dst = o;
  }
}

// ---------------------------------------------------------------------------
// NT GEMM: C[m][n] = sum_k A[m][k] * W[n][k].  128x128 tile, BK=32, 4 waves.
// sect = blockIdx.y / blocksPerSect selects the 1024-col weight section.
// If vtb != nullptr, sect==2 (the V projection) is written TRANSPOSED to
// vtb as [bh=32][d=64][l=2048] bf16 (vectorized over 4 consecutive l).
// ---------------------------------------------------------------------------
template <typename TOUT>
__global__ __launch_bounds__(256) void gemm_nt(const bf16_t* __restrict__ A,
                                               const bf16_t* __restrict__ W,
                                               TOUT* __restrict__ C, int K, int ldc,
                                               int blocksPerSect, bf16_t* __restrict__ vtb) {
  __shared__ bf16_t As[128 * 32];
  __shared__ bf16_t Bs[128 * 32];
  const int t = threadIdx.x;
  const int l = t & 63, w = t >> 6;
  const int wm = w >> 1, wn = w & 1;
  const int lr = l & 15, lg = l >> 4;
  const int bm = blockIdx.x;
  const int by = blockIdx.y;
  const int sect = by / blocksPerSect;
  const int bn = by - sect * blocksPerSect;
  const bf16_t* Wp = W + ((size_t)sect << 20);
  const int n0 = sect * 1024 + bn * 128;

  const bf16_t* ag = A + (size_t)(bm * 128 + (t >> 2)) * K + (t & 3) * 8;
  const bf16_t* bg = Wp + (size_t)(bn * 128 + (t >> 2)) * K + (t & 3) * 8;
  const size_t rs64 = (size_t)64 * K;

  f32x4 acc[4][4];
#pragma unroll
  for (int i = 0; i < 4; ++i)
#pragma unroll
    for (int j = 0; j < 4; ++j) acc[i][j] = (f32x4){0.f, 0.f, 0.f, 0.f};

  for (int k0 = 0; k0 < K; k0 += 32) {
    __syncthreads();
    gload16(ag, As + t * 8);
    gload16(ag + rs64, As + 2048 + t * 8);
    gload16(bg, Bs + t * 8);
    gload16(bg + rs64, Bs + 2048 + t * 8);
    ag += 32;
    bg += 32;
    __syncthreads();
    bf16x8 af[4], bfr[4];
#pragma unroll
    for (int mf = 0; mf < 4; ++mf)
      af[mf] = *(const bf16x8*)(As + (wm * 64 + mf * 16 + lr) * 32 + lg * 8);
#pragma unroll
    for (int nf = 0; nf < 4; ++nf)
      bfr[nf] = *(const bf16x8*)(Bs + (wn * 64 + nf * 16 + lr) * 32 + lg * 8);
#pragma unroll
    for (int mf = 0; mf < 4; ++mf)
#pragma unroll
      for (int nf = 0; nf < 4; ++nf)
        acc[mf][nf] = MFMA_BF16(af[mf], bfr[nf], acc[mf][nf]);
  }

  if (vtb != nullptr && sect == 2) {
#pragma unroll
    for (int mf = 0; mf < 4; ++mf)
#pragma unroll
      for (int nf = 0; nf < 4; ++nf) {
        int row0 = bm * 128 + wm * 64 + mf * 16 + lg * 4;
        int colg = bn * 128 + wn * 64 + nf * 16 + lr;
        int bb = row0 >> 11, ll = row0 & 2047;
        size_t vaddr = ((size_t)((bb * 16 + (colg >> 6)) * 64 + (colg & 63))) * 2048 + ll;
        bf16x4 pk;
#pragma unroll
        for (int j = 0; j < 4; ++j) pk[j] = (bf16_t)acc[mf][nf][j];
        *(bf16x4*)(vtb + vaddr) = pk;
      }
  } else {
#pragma unroll
    for (int mf = 0; mf < 4; ++mf)
#pragma unroll
      for (int nf = 0; nf < 4; ++nf)
#pragma unroll
        for (int j = 0; j < 4; ++j) {
          int row = bm * 128 + wm * 64 + mf * 16 + lg * 4 + j;
          int col = n0 + wn * 64 + nf * 16 + lr;
          C[(size_t)row * ldc + col] = (TOUT)acc[mf][nf][j];
        }
  }
}

// ---------------------------------------------------------------------------
// Flash attention (causal), swapped QK^T, single q-tile/block + K/V dbuf.
// LDS = 2*8K (K) + 2*8K (V) + 8K (P) = 40 KB -> 4 blocks/CU.
// P tile: per-wave [q=16][kv=64] with per-row XOR swizzle byte^=(lr&7)<<4.
// ---------------------------------------------------------------------------
__global__ __launch_bounds__(256) void attn_fwd(const bf16_t* __restrict__ qk,
                                                const bf16_t* __restrict__ vt,
                                                bf16_t* __restrict__ out) {
  __shared__ bf16_t Ks[2][4096];
  __shared__ bf16_t Vts[2][4096];
  __shared__ bf16_t Pt[4][1024];
  const int t = threadIdx.x, l = t & 63, w = t >> 6;
  const int lr = l & 15, lg = l >> 4;
  const int bh = blockIdx.x;
  const int b = bh >> 4, h = bh & 15;
  const int qt = 31 - (int)blockIdx.y;  // heavy tiles first
  const int qloc = w * 16 + lr;
  const int qrow = qt * 64 + qloc;

  // staging addresses (swizzle pre-applied on global source; LDS stays linear)
  const int srow = t >> 3, sc8 = t & 7;
  const int cs = sc8 ^ (srow & 7);
  const bf16_t* kbase = qk + ((size_t)(b * 2048 + srow)) * 2048 + 1024 + h * 64 + cs * 8;
  const bf16_t* vbase = vt + ((size_t)(bh * 64 + srow)) * 2048 + cs * 8;

#define STAGE(ktile, buf)                                              \
  do {                                                                 \
    const bf16_t* ks_ = kbase + (size_t)(ktile) * (64 * 2048);         \
    const bf16_t* vs_ = vbase + (size_t)(ktile) * 64;                  \
    gload16(ks_, &Ks[buf][t * 8]);                                     \
    gload16(ks_ + (size_t)32 * 2048, &Ks[buf][2048 + t * 8]);          \
    gload16(vs_, &Vts[buf][t * 8]);                                    \
    gload16(vs_ + (size_t)32 * 2048, &Vts[buf][2048 + t * 8]);         \
  } while (0)

  // Q fragment, pre-scaled by 1/8 (exact in bf16)
  const bf16_t* Qg = qk + (size_t)(b * 2048 + qrow) * 2048 + h * 64 + lg * 8;
  bf16x8 qf0 = *(const bf16x8*)(Qg);
  bf16x8 qf1 = *(const bf16x8*)(Qg + 32);
#pragma unroll
  for (int j = 0; j < 8; ++j) {
    qf0[j] = (bf16_t)((float)qf0[j] * 0.125f);
    qf1[j] = (bf16_t)((float)qf1[j] * 0.125f);
  }

  f32x4 acc[4];
#pragma unroll
  for (int df = 0; df < 4; ++df) acc[df] = (f32x4){0.f, 0.f, 0.f, 0.f};
  float m_r = -1e30f, l_r = 0.f;

  // P-tile swizzled addresses (bytes), per-wave region
  char* PwB = (char*)&Pt[w][0];
  const int psw = (lr & 7) << 4;

  STAGE(0, 0);
  __syncthreads();

  int cur = 0;
  for (int kt = 0; kt <= qt; ++kt) {
    if (kt < qt) STAGE(kt + 1, cur ^ 1);

    // --- S^T = K (Q/8)^T : rows = kv, cols = q(=lr) ---
    f32x4 sc[4];
#pragma unroll
    for (int nf = 0; nf < 4; ++nf) sc[nf] = (f32x4){0.f, 0.f, 0.f, 0.f};
    __builtin_amdgcn_s_setprio(1);
#pragma unroll
    for (int nf = 0; nf < 4; ++nf) {
      int row = nf * 16 + lr, r7 = row & 7;
      bf16x8 kf0 = *(const bf16x8*)(&Ks[cur][row * 64 + (lg ^ r7) * 8]);
      bf16x8 kf1 = *(const bf16x8*)(&Ks[cur][row * 64 + ((lg ^ 4) ^ r7) * 8]);
      sc[nf] = MFMA_BF16(kf0, qf0, sc[nf]);
      sc[nf] = MFMA_BF16(kf1, qf1, sc[nf]);
    }
    __builtin_amdgcn_s_setprio(0);

    float s[16];
#pragma unroll
    for (int nf = 0; nf < 4; ++nf)
#pragma unroll
      for (int j = 0; j < 4; ++j) s[nf * 4 + j] = sc[nf][j];
    if (kt == qt) {
#pragma unroll
      for (int nf = 0; nf < 4; ++nf)
#pragma unroll
        for (int j = 0; j < 4; ++j)
          if (nf * 16 + lg * 4 + j > qloc) s[nf * 4 + j] = -1e30f;
    }

    // --- online softmax in exp2 domain; lane owns one q row ---
    float t0 = fmaxf(fmaxf(s[0], s[1]), fmaxf(s[2], s[3]));
    float t1 = fmaxf(fmaxf(s[4], s[5]), fmaxf(s[6], s[7]));
    float t2 = fmaxf(fmaxf(s[8], s[9]), fmaxf(s[10], s[11]));
    float t3 = fmaxf(fmaxf(s[12], s[13]), fmaxf(s[14], s[15]));
    float m16 = fmaxf(fmaxf(t0, t1), fmaxf(t2, t3));
    float rm = fmaxf(m16, __shfl_xor(m16, 16));
    rm = fmaxf(rm, __shfl_xor(rm, 32));
    if (!__all(rm - m_r <= 8.f)) {  // defer-max
      float mnew = fmaxf(m_r, rm);
      float sf = __builtin_amdgcn_exp2f((m_r - mnew) * LOG2E);
      m_r = mnew;
      l_r *= sf;
#pragma unroll
      for (int df = 0; df < 4; ++df)
#pragma unroll
        for (int j = 0; j < 4; ++j) acc[df][j] *= sf;
    }
    const float m2 = m_r * LOG2E;
    float p[16], ps = 0.f;
#pragma unroll
    for (int i = 0; i < 16; ++i) {
      p[i] = __builtin_amdgcn_exp2f(fmaf(s[i], LOG2E, -m2));
      ps += p[i];
    }
    ps += __shfl_xor(ps, 16);
    ps += __shfl_xor(ps, 32);
    l_r += ps;

    // --- P -> LDS (swizzled bf16x4 writes) ---
#pragma unroll
    for (int nf = 0; nf < 4; ++nf) {
      bf16x4 pk;
#pragma unroll
      for (int j = 0; j < 4; ++j) pk[j] = (bf16_t)p[nf * 4 + j];
      *(bf16x4*)(PwB + lr * 128 + ((nf * 32 + lg * 8) ^ psw)) = pk;
    }

    // --- O^T += Vt P^T ---
    bf16x8 pb0 = *(const bf16x8*)(PwB + lr * 128 + ((lg * 16) ^ psw));
    bf16x8 pb1 = *(const bf16x8*)(PwB + lr * 128 + ((64 + lg * 16) ^ psw));
    __builtin_amdgcn_s_setprio(1);
#pragma unroll
    for (int df = 0; df < 4; ++df) {
      int arow = df * 16 + lr, r7 = arow & 7;
      bf16x8 vf0 = *(const bf16x8*)(&Vts[cur][arow * 64 + (lg ^ r7) * 8]);
      bf16x8 vf1 = *(const bf16x8*)(&Vts[cur][arow * 64 + ((lg ^ 4) ^ r7) * 8]);
      acc[df] = MFMA_BF16(vf0, pb0, acc[df]);
      acc[df] = MFMA_BF16(vf1, pb1, acc[df]);
    }
    __builtin_amdgcn_s_setprio(0);
    __syncthreads();
    cur ^= 1;
  }
#undef STAGE

  // --- normalize + write (lane owns q row; d contiguous over j) ---
  float inv = 1.f / l_r;
#pragma unroll
  for (int df = 0; df < 4; ++df) {
    bf16x4 o;
#pragma unroll
    for (int j = 0; j < 4; ++j) o[j] = (bf16_t)(acc[df][j] * inv);
    *(bf16x4*)(out + (size_t)(b * 2048 + qrow) * 1024 + h * 64 + df * 16 + lg * 4) = o;
  }
}

// ---------------------------------------------------------------------------
extern "C" void kernel_launch(void* const* d_in, const int* in_sizes, int n_in,
                              void* d_out, int out_size, void* d_ws, size_t ws_size,
                              hipStream_t stream) {
  const float* x = (const float*)d_in[0];
  const float* wk = (const float*)d_in[1];
  const float* wq = (const float*)d_in[2];
  const float* wv = (const float*)d_in[3];
  const float* wo = (const float*)d_in[4];

  bf16_t* xbf = (bf16_t*)d_ws;           // 4 Mi elems (8 MB)
  bf16_t* wbf = xbf + 4194304;           // 4 Mi elems (8 MB): [Wq|Wk|Wv|Wo]
  bf16_t* qkbf = wbf + 4194304;          // 8 Mi elems (16 MB): [Q|K] cols
  bf16_t* vtbuf = qkbf + 8388608;        // 4 Mi elems (8 MB): V transposed
  bf16_t* attnbf = xbf;                  // alias: xbf dead after QKV gemm
  float* out = (float*)d_out;

  cast_all<<<dim3(2048), dim3(256), 0, stream>>>(x, wk, wq, wv, wo, xbf, wbf);
  gemm_nt<bf16_t><<<dim3(32, 24), dim3(256), 0, stream>>>(xbf, wbf, qkbf, 1024, 2048, 8, vtbuf);
  attn_fwd<<<dim3(32, 32), dim3(256), 0, stream>>>(qkbf, vtbuf, attnbf);
  gemm_nt<float><<<dim3(32, 8), dim3(256), 0, stream>>>(attnbf, wbf + 3 * 1048576, out, 1024,
                                                        1024, 8, (bf16_t*)nullptr);
}